// Round 11
// baseline (215.403 us; speedup 1.0000x reference)
//
#include <hip/hip_runtime.h>
#include <cfloat>

// VQ-VAE nearest-codebook via bf16x3 split MFMA, v7 "4 waves/SIMD":
//   - 64 rows/block (2 accs/wave), grid 512 = 2 blocks/CU = 4 waves/SIMD
//   - barrier-free global-direct fragment loads (L2-resident split codebook)
//   - C-init with r2n = -||e||^2/2 -> argmax(acc), cheap tree-max epilogue
// d_out (f32): [0,NQ) quantized | [NQ] vq_loss | [NQ+1] commitment | [NQ+2,+N) idx
// d_ws  (f32): [0,K) r2n | [K] loss | [8448...) split codebook (2 MB)

typedef __bf16 bf16x8 __attribute__((ext_vector_type(8)));
typedef float  f32x16 __attribute__((ext_vector_type(16)));

constexpr int N_ROWS = 32768;
constexpr int K_CB   = 8192;
constexpr int D_DIM  = 64;
constexpr size_t NQ  = (size_t)N_ROWS * D_DIM;
constexpr int WS_LOSS = K_CB;
constexpr size_t WS_SPLIT_F   = 8448;
constexpr size_t SPLIT_BYTES  = (size_t)K_CB * D_DIM * 4;   // 2 MB
constexpr size_t WS_NEED      = WS_SPLIT_F * 4 + SPLIT_BYTES;
constexpr int NROUND = K_CB / 256;                          // 32 rounds of 256 codes

// ---------------------------------------------------------------- prep: r2n
__global__ __launch_bounds__(256) void vq_prep(const float* __restrict__ cb,
                                               float* __restrict__ ws) {
  const int k = blockIdx.x * 256 + threadIdx.x;
  if (k == 0) ws[WS_LOSS] = 0.0f;
  const float4* p = reinterpret_cast<const float4*>(cb) + (size_t)k * 16;
  float s0 = 0.f, s1 = 0.f, s2 = 0.f, s3 = 0.f;
#pragma unroll
  for (int j = 0; j < 16; ++j) {
    float4 v = p[j];
    s0 = fmaf(v.x, v.x, s0); s1 = fmaf(v.y, v.y, s1);
    s2 = fmaf(v.z, v.z, s2); s3 = fmaf(v.w, v.w, s3);
  }
  ws[k] = -0.5f * ((s0 + s1) + (s2 + s3));   // r2n = -r2/2
}

// ------------------------------------------------- prep: split codebook in ws
// Round r (256 codes) -> 64KB block: t(=k>>5&7)*8192 + h*4096 + ch*512 + c*16.
__global__ __launch_bounds__(256) void vq_split(const float* __restrict__ cb,
                                                float* __restrict__ ws) {
  const int u  = blockIdx.x * 256 + threadIdx.x;   // 65536 threads
  const int k  = u >> 3, ch = u & 7;
  const int r  = k >> 8, t = (k >> 5) & 7, c = k & 31;
  const float* src = cb + (size_t)k * D_DIM + ch * 8;
  float4 f0 = *reinterpret_cast<const float4*>(src);
  float4 f1 = *reinterpret_cast<const float4*>(src + 4);
  float xs[8] = {f0.x, f0.y, f0.z, f0.w, f1.x, f1.y, f1.z, f1.w};
  bf16x8 hi, lo;
#pragma unroll
  for (int j = 0; j < 8; ++j) {
    __bf16 h = (__bf16)xs[j];
    hi[j] = h;
    lo[j] = (__bf16)(xs[j] - (float)h);
  }
  char* base = reinterpret_cast<char*>(ws + WS_SPLIT_F) +
               (size_t)r * 65536 + (size_t)t * 8192 + (size_t)ch * 512 + (size_t)c * 16;
  *reinterpret_cast<bf16x8*>(base)        = hi;
  *reinterpret_cast<bf16x8*>(base + 4096) = lo;
}

// ---------------------------------------------------------------- main kernel
// 512 thr = 8 waves; wave w = code-tile w (32 codes/round); 2 row-accs
// (rows rowbase + q*32 + c, q=0,1). Grid 512 -> 2 blocks/CU, 4 waves/SIMD.
__global__ __launch_bounds__(512, 4) void vq_gd3(const float* __restrict__ z,
                                                 const float* __restrict__ cb,
                                                 float* __restrict__ ws,
                                                 float* __restrict__ out) {
  __shared__ __attribute__((aligned(16))) unsigned char lds[8192];

  const int tid = threadIdx.x;
  const int w = tid >> 6, l = tid & 63;
  const int c = l & 31, g = l >> 5;
  const int rowbase = blockIdx.x * 64;

  // --- z fragments: 2 rowsets x 4 k-steps, hi/lo split, registers forever ---
  bf16x8 zh[2][4], zl[2][4];
#pragma unroll
  for (int q = 0; q < 2; ++q) {
    const float* zr = z + (size_t)(rowbase + q * 32 + c) * D_DIM + 8 * g;
#pragma unroll
    for (int s = 0; s < 4; ++s) {
      float4 f0 = *reinterpret_cast<const float4*>(zr + 16 * s);
      float4 f1 = *reinterpret_cast<const float4*>(zr + 16 * s + 4);
      float xs[8] = {f0.x, f0.y, f0.z, f0.w, f1.x, f1.y, f1.z, f1.w};
#pragma unroll
      for (int j = 0; j < 8; ++j) {
        __bf16 h = (__bf16)xs[j];
        zh[q][s][j] = h;
        zl[q][s][j] = (__bf16)(xs[j] - (float)h);
      }
    }
  }

  // code-fragment pointers for my tile: hi at +s*1024, lo +4096
  const char* hp = reinterpret_cast<const char*>(ws + WS_SPLIT_F) +
                   (size_t)w * 8192 + (size_t)g * 512 + (size_t)c * 16;
  const char* lq = hp + 4096;
  const float* rp = ws + w * 32 + 4 * g;

  // prologue: round-0 fragments + r2n
  bf16x8 fh[4], fl[4];
#pragma unroll
  for (int s = 0; s < 4; ++s) {
    fh[s] = *reinterpret_cast<const bf16x8*>(hp + s * 1024);
    fl[s] = *reinterpret_cast<const bf16x8*>(lq + s * 1024);
  }
  float4 rv0 = *reinterpret_cast<const float4*>(rp);
  float4 rv1 = *reinterpret_cast<const float4*>(rp + 8);
  float4 rv2 = *reinterpret_cast<const float4*>(rp + 16);
  float4 rv3 = *reinterpret_cast<const float4*>(rp + 24);

  float gbest0 = -FLT_MAX, gbest1 = -FLT_MAX;
  int   bp0 = 0, bp1 = 0;   // (round<<4) | i

  for (int r = 0; r < NROUND; ++r) {
    // C-init: acc = r2n (same 16 codes for both row-accs)
    f32x16 ainit;
    ainit[0]  = rv0.x; ainit[1]  = rv0.y; ainit[2]  = rv0.z; ainit[3]  = rv0.w;
    ainit[4]  = rv1.x; ainit[5]  = rv1.y; ainit[6]  = rv1.z; ainit[7]  = rv1.w;
    ainit[8]  = rv2.x; ainit[9]  = rv2.y; ainit[10] = rv2.z; ainit[11] = rv2.w;
    ainit[12] = rv3.x; ainit[13] = rv3.y; ainit[14] = rv3.z; ainit[15] = rv3.w;
    f32x16 a0 = ainit, a1 = ainit;

    __builtin_amdgcn_s_setprio(1);
#pragma unroll
    for (int s = 0; s < 4; ++s) {
      a0 = __builtin_amdgcn_mfma_f32_32x32x16_bf16(fh[s], zh[0][s], a0, 0, 0, 0);
      a1 = __builtin_amdgcn_mfma_f32_32x32x16_bf16(fh[s], zh[1][s], a1, 0, 0, 0);
      a0 = __builtin_amdgcn_mfma_f32_32x32x16_bf16(fh[s], zl[0][s], a0, 0, 0, 0);
      a1 = __builtin_amdgcn_mfma_f32_32x32x16_bf16(fh[s], zl[1][s], a1, 0, 0, 0);
      a0 = __builtin_amdgcn_mfma_f32_32x32x16_bf16(fl[s], zh[0][s], a0, 0, 0, 0);
      a1 = __builtin_amdgcn_mfma_f32_32x32x16_bf16(fl[s], zh[1][s], a1, 0, 0, 0);
    }
    __builtin_amdgcn_s_setprio(0);

    // prefetch next round (WAR after cluster reads; latency hides under epilogue)
    if (r < NROUND - 1) {
      hp += 65536; lq += 65536; rp += 256;
#pragma unroll
      for (int s = 0; s < 4; ++s) {
        fh[s] = *reinterpret_cast<const bf16x8*>(hp + s * 1024);
        fl[s] = *reinterpret_cast<const bf16x8*>(lq + s * 1024);
      }
      rv0 = *reinterpret_cast<const float4*>(rp);
      rv1 = *reinterpret_cast<const float4*>(rp + 8);
      rv2 = *reinterpret_cast<const float4*>(rp + 16);
      rv3 = *reinterpret_cast<const float4*>(rp + 24);
    }

    // epilogue: per acc, tree-max -> first-i equality scan -> global update
    const int pb = r << 4;
    {
      float m = a0[0];
#pragma unroll
      for (int i = 1; i < 16; ++i) m = fmaxf(m, a0[i]);
      int bi = 0;
#pragma unroll
      for (int i = 15; i >= 0; --i) bi = (a0[i] == m) ? i : bi;  // smallest i
      bool upd = m > gbest0;
      gbest0 = upd ? m : gbest0;
      bp0    = upd ? (pb + bi) : bp0;
    }
    {
      float m = a1[0];
#pragma unroll
      for (int i = 1; i < 16; ++i) m = fmaxf(m, a1[i]);
      int bi = 0;
#pragma unroll
      for (int i = 15; i >= 0; --i) bi = (a1[i] == m) ? i : bi;
      bool upd = m > gbest1;
      gbest1 = upd ? m : gbest1;
      bp1    = upd ? (pb + bi) : bp1;
    }
  }

  // --- decode packed (round,i) -> global k, then exact-tie merges (max) ---
  int bk0, bk1;
  {
    int rr = bp0 >> 4, i = bp0 & 15;
    bk0 = rr * 256 + w * 32 + (i & 3) + 8 * (i >> 2) + 4 * g;
    rr = bp1 >> 4; i = bp1 & 15;
    bk1 = rr * 256 + w * 32 + (i & 3) + 8 * (i >> 2) + 4 * g;
  }
  // merge the two g-halves (same rows, disjoint codes)
  {
    float ob = __shfl_xor(gbest0, 32, 64);
    int   ok = __shfl_xor(bk0, 32, 64);
    if (ob > gbest0 || (ob == gbest0 && ok < bk0)) { gbest0 = ob; bk0 = ok; }
    ob = __shfl_xor(gbest1, 32, 64);
    ok = __shfl_xor(bk1, 32, 64);
    if (ob > gbest1 || (ob == gbest1 && ok < bk1)) { gbest1 = ob; bk1 = ok; }
  }

  // cross-wave merge: 8 tile-waves x 64 rows
  float* fbuf = reinterpret_cast<float*>(lds);          // [8][64]  2KB
  int*   kbuf = reinterpret_cast<int*>(lds + 2048);     // [8][64]  2KB
  int*   ibuf = reinterpret_cast<int*>(lds + 4096);     // [64]
  if (l < 32) {
    fbuf[w * 64 + c]      = gbest0;  kbuf[w * 64 + c]      = bk0;
    fbuf[w * 64 + 32 + c] = gbest1;  kbuf[w * 64 + 32 + c] = bk1;
  }
  __syncthreads();

  if (tid < 64) {
    float bb = fbuf[tid];
    int   kk = kbuf[tid];
#pragma unroll
    for (int ww = 1; ww < 8; ++ww) {
      float b2 = fbuf[ww * 64 + tid];
      int   k2 = kbuf[ww * 64 + tid];
      if (b2 > bb || (b2 == bb && k2 < kk)) { bb = b2; kk = k2; }
    }
    ibuf[tid] = kk;
    out[NQ + 2 + rowbase + tid] = (float)kk;
  }
  __syncthreads();

  // --- gather + losses: 8 threads per row (8 f32 each) ---
  {
    const int row_l = tid >> 3, seg = tid & 7;
    const int idx  = ibuf[row_l];
    const int grow = rowbase + row_l;
    const float4* qp = reinterpret_cast<const float4*>(cb + (size_t)idx * D_DIM + seg * 8);
    const float4* zp = reinterpret_cast<const float4*>(z + (size_t)grow * D_DIM + seg * 8);
    float4*       op = reinterpret_cast<float4*>(out + (size_t)grow * D_DIM + seg * 8);
    float lp = 0.f;
#pragma unroll
    for (int cc = 0; cc < 2; ++cc) {
      float4 qv = qp[cc], zv = zp[cc];
      op[cc] = qv;
      float dx = zv.x - qv.x, dy = zv.y - qv.y;
      float dz = zv.z - qv.z, dw = zv.w - qv.w;
      lp += (dx * dx + dy * dy) + (dz * dz + dw * dw);
    }
#pragma unroll
    for (int off = 32; off > 0; off >>= 1) lp += __shfl_down(lp, off, 64);
    if (l == 0) atomicAdd(ws + WS_LOSS, lp);
  }
}

// ------------------------------------------------- fallback (R4-style; adapted
// to r2n semantics: score = r2n + dot, maximize)
__global__ __launch_bounds__(512, 2) void vq_main_reg(const float* __restrict__ z,
                                                      const float* __restrict__ cb,
                                                      float* __restrict__ ws,
                                                      float* __restrict__ out) {
  __shared__ __attribute__((aligned(16))) unsigned char lds[65536];
  const int tid = threadIdx.x;
  const int w = tid >> 6, l = tid & 63;
  const int rg = w >> 1, sp = w & 1;
  const int c = l & 31, g = l >> 5;
  const int rowbase = blockIdx.x * 128;
  const int myrow = rowbase + rg * 32 + c;

  bf16x8 zh[4], zl[4];
#pragma unroll
  for (int s = 0; s < 4; ++s) {
    const float* zp = z + (size_t)myrow * D_DIM + 16 * s + 8 * g;
    float4 f0 = *reinterpret_cast<const float4*>(zp);
    float4 f1 = *reinterpret_cast<const float4*>(zp + 4);
    float xs[8] = {f0.x, f0.y, f0.z, f0.w, f1.x, f1.y, f1.z, f1.w};
#pragma unroll
    for (int j = 0; j < 8; ++j) {
      __bf16 h = (__bf16)xs[j];
      zh[s][j] = h; zl[s][j] = (__bf16)(xs[j] - (float)h);
    }
  }
  const int st_t01 = tid >> 8;
  const int st_c   = (tid >> 3) & 31;
  const int st_ch  = tid & 7;
  const unsigned st_off = (unsigned)(st_t01 * 16384 + st_ch * 512 + st_c * 16);
  const float* st_g = cb + (size_t)(st_t01 * 32 + st_c) * D_DIM + st_ch * 8;

  float best = -FLT_MAX;
  int   bidx = 0;
  float4 p0 = *reinterpret_cast<const float4*>(st_g);
  float4 p1 = *reinterpret_cast<const float4*>(st_g + 4);
  {
    float xs[8] = {p0.x, p0.y, p0.z, p0.w, p1.x, p1.y, p1.z, p1.w};
    bf16x8 hi, lo;
#pragma unroll
    for (int j = 0; j < 8; ++j) {
      __bf16 h = (__bf16)xs[j];
      hi[j] = h; lo[j] = (__bf16)(xs[j] - (float)h);
    }
    *reinterpret_cast<bf16x8*>(lds + st_off)        = hi;
    *reinterpret_cast<bf16x8*>(lds + st_off + 8192) = lo;
  }
  __syncthreads();
  const unsigned rd_base = (unsigned)(sp * 16384 + c * 16);
  for (int r = 0; r < 128; ++r) {
    const int buf = r & 1;
    if (r < 127) {
      const float* gp = st_g + (size_t)(r + 1) * (64 * D_DIM);
      p0 = *reinterpret_cast<const float4*>(gp);
      p1 = *reinterpret_cast<const float4*>(gp + 4);
    }
    const unsigned b0 = (unsigned)buf * 32768u + rd_base;
    bf16x8 ch[4], cl[4];
#pragma unroll
    for (int s = 0; s < 4; ++s) {
      unsigned off = b0 + (unsigned)((2 * s + g) * 512);
      ch[s] = *reinterpret_cast<const bf16x8*>(lds + off);
      cl[s] = *reinterpret_cast<const bf16x8*>(lds + off + 8192);
    }
    f32x16 acc;
#pragma unroll
    for (int i = 0; i < 16; ++i) acc[i] = 0.f;
#pragma unroll
    for (int s = 0; s < 4; ++s) {
      acc = __builtin_amdgcn_mfma_f32_32x32x16_bf16(ch[s], zh[s], acc, 0, 0, 0);
      acc = __builtin_amdgcn_mfma_f32_32x32x16_bf16(ch[s], zl[s], acc, 0, 0, 0);
      acc = __builtin_amdgcn_mfma_f32_32x32x16_bf16(cl[s], zh[s], acc, 0, 0, 0);
    }
    const int tb = (2 * r + sp) * 32 + 4 * g;
#pragma unroll
    for (int q = 0; q < 4; ++q) {
      float4 rv = *reinterpret_cast<const float4*>(ws + tb + 8 * q);
      float ra[4] = {rv.x, rv.y, rv.z, rv.w};
#pragma unroll
      for (int j = 0; j < 4; ++j) {
        float sc = ra[j] + acc[4 * q + j];   // r2n + dot, maximize
        int kg = tb + 8 * q + j;
        if (sc > best) { best = sc; bidx = kg; }
      }
    }
    if (r < 127) {
      float xs[8] = {p0.x, p0.y, p0.z, p0.w, p1.x, p1.y, p1.z, p1.w};
      bf16x8 hi, lo;
#pragma unroll
      for (int j = 0; j < 8; ++j) {
        __bf16 h = (__bf16)xs[j];
        hi[j] = h; lo[j] = (__bf16)(xs[j] - (float)h);
      }
      unsigned wo = (unsigned)(buf ^ 1) * 32768u + st_off;
      *reinterpret_cast<bf16x8*>(lds + wo)        = hi;
      *reinterpret_cast<bf16x8*>(lds + wo + 8192) = lo;
    }
    __syncthreads();
  }
  {
    float ob = __shfl_xor(best, 32, 64);
    int   oi = __shfl_xor(bidx, 32, 64);
    if (ob > best || (ob == best && oi < bidx)) { best = ob; bidx = oi; }
  }
  float* mf  = reinterpret_cast<float*>(lds);
  int*   mi  = reinterpret_cast<int*>(lds + 1024);
  int*   mix = reinterpret_cast<int*>(lds + 2048);
  if (l < 32) { mf[w * 32 + c] = best; mi[w * 32 + c] = bidx; }
  __syncthreads();
  if (tid < 128) {
    int rgg = tid >> 5, rl = tid & 31;
    float b0 = mf[(2 * rgg) * 32 + rl];     int i0 = mi[(2 * rgg) * 32 + rl];
    float b1 = mf[(2 * rgg + 1) * 32 + rl]; int i1 = mi[(2 * rgg + 1) * 32 + rl];
    int idx = (b1 > b0 || (b1 == b0 && i1 < i0)) ? i1 : i0;
    mix[tid] = idx;
    out[NQ + 2 + rowbase + tid] = (float)idx;
  }
  __syncthreads();
  {
    const int row_l = tid >> 2, seg = tid & 3;
    const int idx  = mix[row_l];
    const int grow = rowbase + row_l;
    const float4* qp = reinterpret_cast<const float4*>(cb + (size_t)idx * D_DIM + seg * 16);
    const float4* zp = reinterpret_cast<const float4*>(z + (size_t)grow * D_DIM + seg * 16);
    float4*       op = reinterpret_cast<float4*>(out + (size_t)grow * D_DIM + seg * 16);
    float lp = 0.f;
#pragma unroll
    for (int cc = 0; cc < 4; ++cc) {
      float4 qv = qp[cc], zv = zp[cc];
      op[cc] = qv;
      float dx = zv.x - qv.x, dy = zv.y - qv.y;
      float dz = zv.z - qv.z, dw = zv.w - qv.w;
      lp += (dx * dx + dy * dy) + (dz * dz + dw * dw);
    }
#pragma unroll
    for (int off = 32; off > 0; off >>= 1) lp += __shfl_down(lp, off, 64);
    if (l == 0) atomicAdd(ws + WS_LOSS, lp);
  }
}

// ------------------------------------------------------------ finalize kernel
__global__ void vq_fin(const float* __restrict__ ws, float* __restrict__ out) {
  float mm = ws[WS_LOSS] * (1.0f / (float)(N_ROWS * D_DIM));
  out[NQ]     = mm;
  out[NQ + 1] = mm;
}

// -------------------------------------------------------------------- launch
extern "C" void kernel_launch(void* const* d_in, const int* in_sizes, int n_in,
                              void* d_out, int out_size, void* d_ws, size_t ws_size,
                              hipStream_t stream) {
  (void)in_sizes; (void)n_in; (void)out_size;
  const float* z  = (const float*)d_in[0];
  const float* cb = (const float*)d_in[1];
  float* out = (float*)d_out;
  float* ws  = (float*)d_ws;

  vq_prep<<<K_CB / 256, 256, 0, stream>>>(cb, ws);
  if (ws_size >= WS_NEED) {
    vq_split<<<256, 256, 0, stream>>>(cb, ws);
    vq_gd3<<<N_ROWS / 64, 512, 0, stream>>>(z, cb, ws, out);
  } else {
    vq_main_reg<<<N_ROWS / 128, 512, 0, stream>>>(z, cb, ws, out);
  }
  vq_fin<<<1, 1, 0, stream>>>(ws, out);
}

// Round 12
// 160.803 us; speedup vs baseline: 1.3395x; 1.3395x over previous
//
#include <hip/hip_runtime.h>
#include <cfloat>

// VQ-VAE nearest-codebook via bf16x3 split MFMA, v8 "z-in-LDS, 4 waves/SIMD":
//   - all 8 waves in a block share the same 64 rows -> z hi/lo lives in LDS
//     (16 KB, staged once); waves re-read fragments per round (cheap, hidden)
//   - code fragments + r2n load JIT from L2 (no prefetch regs) -> ~116 VGPR,
//     fits 4 waves/SIMD without spill (R11 spilled at ~154 regs)
//   - barrier-free main loop; C-init r2n argmax epilogue (R10/R11-proven)
// d_out (f32): [0,NQ) quantized | [NQ] vq_loss | [NQ+1] commitment | [NQ+2,+N) idx
// d_ws  (f32): [0,K) r2n | [K] loss | [8448...) split codebook (2 MB)

typedef __bf16 bf16x8 __attribute__((ext_vector_type(8)));
typedef float  f32x16 __attribute__((ext_vector_type(16)));

constexpr int N_ROWS = 32768;
constexpr int K_CB   = 8192;
constexpr int D_DIM  = 64;
constexpr size_t NQ  = (size_t)N_ROWS * D_DIM;
constexpr int WS_LOSS = K_CB;
constexpr size_t WS_SPLIT_F   = 8448;
constexpr size_t SPLIT_BYTES  = (size_t)K_CB * D_DIM * 4;   // 2 MB
constexpr size_t WS_NEED      = WS_SPLIT_F * 4 + SPLIT_BYTES;
constexpr int NROUND = K_CB / 256;                          // 32 rounds of 256 codes

// ---------------------------------------------------------------- prep: r2n
__global__ __launch_bounds__(256) void vq_prep(const float* __restrict__ cb,
                                               float* __restrict__ ws) {
  const int k = blockIdx.x * 256 + threadIdx.x;
  if (k == 0) ws[WS_LOSS] = 0.0f;
  const float4* p = reinterpret_cast<const float4*>(cb) + (size_t)k * 16;
  float s0 = 0.f, s1 = 0.f, s2 = 0.f, s3 = 0.f;
#pragma unroll
  for (int j = 0; j < 16; ++j) {
    float4 v = p[j];
    s0 = fmaf(v.x, v.x, s0); s1 = fmaf(v.y, v.y, s1);
    s2 = fmaf(v.z, v.z, s2); s3 = fmaf(v.w, v.w, s3);
  }
  ws[k] = -0.5f * ((s0 + s1) + (s2 + s3));   // r2n = -r2/2
}

// ------------------------------------------------- prep: split codebook in ws
// Round r (256 codes) -> 64KB block: t(=k>>5&7)*8192 + h*4096 + ch*512 + c*16.
__global__ __launch_bounds__(256) void vq_split(const float* __restrict__ cb,
                                                float* __restrict__ ws) {
  const int u  = blockIdx.x * 256 + threadIdx.x;   // 65536 threads
  const int k  = u >> 3, ch = u & 7;
  const int r  = k >> 8, t = (k >> 5) & 7, c = k & 31;
  const float* src = cb + (size_t)k * D_DIM + ch * 8;
  float4 f0 = *reinterpret_cast<const float4*>(src);
  float4 f1 = *reinterpret_cast<const float4*>(src + 4);
  float xs[8] = {f0.x, f0.y, f0.z, f0.w, f1.x, f1.y, f1.z, f1.w};
  bf16x8 hi, lo;
#pragma unroll
  for (int j = 0; j < 8; ++j) {
    __bf16 h = (__bf16)xs[j];
    hi[j] = h;
    lo[j] = (__bf16)(xs[j] - (float)h);
  }
  char* base = reinterpret_cast<char*>(ws + WS_SPLIT_F) +
               (size_t)r * 65536 + (size_t)t * 8192 + (size_t)ch * 512 + (size_t)c * 16;
  *reinterpret_cast<bf16x8*>(base)        = hi;
  *reinterpret_cast<bf16x8*>(base + 4096) = lo;
}

// ---------------------------------------------------------------- main kernel
// 512 thr = 8 waves; wave w = code-tile w (32 codes/round); 2 row-accs
// (rows rowbase + q*32 + c). z hi/lo shared in LDS. Grid 512, 4 waves/SIMD.
__global__ __launch_bounds__(512, 4) void vq_gd4(const float* __restrict__ z,
                                                 const float* __restrict__ cb,
                                                 float* __restrict__ ws,
                                                 float* __restrict__ out) {
  __shared__ __attribute__((aligned(16))) unsigned char lds[16384];
  // zh at [0,8K): slot(q,s,g,c) = q*4096 + s*1024 + g*512 + c*16 ; zl at +8K.

  const int tid = threadIdx.x;
  const int w = tid >> 6, l = tid & 63;
  const int c = l & 31, g = l >> 5;
  const int rowbase = blockIdx.x * 64;

  // ---- stage z hi/lo into LDS (once; each thread fills one 16B slot) ----
  {
    const int sc = tid & 31;
    const int sg = (tid >> 5) & 1;
    const int ss = (tid >> 6) & 3;
    const int sq = tid >> 8;
    const float* zr = z + (size_t)(rowbase + sq * 32 + sc) * D_DIM + 16 * ss + 8 * sg;
    float4 f0 = *reinterpret_cast<const float4*>(zr);
    float4 f1 = *reinterpret_cast<const float4*>(zr + 4);
    float xs[8] = {f0.x, f0.y, f0.z, f0.w, f1.x, f1.y, f1.z, f1.w};
    bf16x8 hi, lo;
#pragma unroll
    for (int j = 0; j < 8; ++j) {
      __bf16 h = (__bf16)xs[j];
      hi[j] = h;
      lo[j] = (__bf16)(xs[j] - (float)h);
    }
    const unsigned off = (unsigned)(sq * 4096 + ss * 1024 + sg * 512 + sc * 16);
    *reinterpret_cast<bf16x8*>(lds + off)        = hi;
    *reinterpret_cast<bf16x8*>(lds + 8192 + off) = lo;
  }
  __syncthreads();

  // code-fragment pointers for my tile: hi at +s*1024, lo +4096
  const char* hp = reinterpret_cast<const char*>(ws + WS_SPLIT_F) +
                   (size_t)w * 8192 + (size_t)g * 512 + (size_t)c * 16;
  const char* lq = hp + 4096;
  const float* rp = ws + w * 32 + 4 * g;

  // lane part of z LDS offsets
  const unsigned zlane = (unsigned)(g * 512 + c * 16);

  float gbest0 = -FLT_MAX, gbest1 = -FLT_MAX;
  int   bp0 = 0, bp1 = 0;   // (round<<4) | i

  for (int r = 0; r < NROUND; ++r) {
    // JIT loads: r2n + code fragments (TLP hides L2 latency at 4 waves/SIMD)
    float4 rv0 = *reinterpret_cast<const float4*>(rp);
    float4 rv1 = *reinterpret_cast<const float4*>(rp + 8);
    float4 rv2 = *reinterpret_cast<const float4*>(rp + 16);
    float4 rv3 = *reinterpret_cast<const float4*>(rp + 24);
    bf16x8 fh[4], fl[4];
#pragma unroll
    for (int s = 0; s < 4; ++s) {
      fh[s] = *reinterpret_cast<const bf16x8*>(hp + s * 1024);
      fl[s] = *reinterpret_cast<const bf16x8*>(lq + s * 1024);
    }
    hp += 65536; lq += 65536; rp += 256;

    // C-init: acc = r2n (same 16 codes for both row-accs)
    f32x16 ainit;
    ainit[0]  = rv0.x; ainit[1]  = rv0.y; ainit[2]  = rv0.z; ainit[3]  = rv0.w;
    ainit[4]  = rv1.x; ainit[5]  = rv1.y; ainit[6]  = rv1.z; ainit[7]  = rv1.w;
    ainit[8]  = rv2.x; ainit[9]  = rv2.y; ainit[10] = rv2.z; ainit[11] = rv2.w;
    ainit[12] = rv3.x; ainit[13] = rv3.y; ainit[14] = rv3.z; ainit[15] = rv3.w;
    f32x16 a0 = ainit, a1 = ainit;

    __builtin_amdgcn_s_setprio(1);
#pragma unroll
    for (int s = 0; s < 4; ++s) {
      const unsigned zo = (unsigned)(s * 1024) + zlane;
      bf16x8 z0h = *reinterpret_cast<const bf16x8*>(lds + zo);
      bf16x8 z1h = *reinterpret_cast<const bf16x8*>(lds + 4096 + zo);
      bf16x8 z0l = *reinterpret_cast<const bf16x8*>(lds + 8192 + zo);
      bf16x8 z1l = *reinterpret_cast<const bf16x8*>(lds + 12288 + zo);
      a0 = __builtin_amdgcn_mfma_f32_32x32x16_bf16(fh[s], z0h, a0, 0, 0, 0);
      a1 = __builtin_amdgcn_mfma_f32_32x32x16_bf16(fh[s], z1h, a1, 0, 0, 0);
      a0 = __builtin_amdgcn_mfma_f32_32x32x16_bf16(fh[s], z0l, a0, 0, 0, 0);
      a1 = __builtin_amdgcn_mfma_f32_32x32x16_bf16(fh[s], z1l, a1, 0, 0, 0);
      a0 = __builtin_amdgcn_mfma_f32_32x32x16_bf16(fl[s], z0h, a0, 0, 0, 0);
      a1 = __builtin_amdgcn_mfma_f32_32x32x16_bf16(fl[s], z1h, a1, 0, 0, 0);
    }
    __builtin_amdgcn_s_setprio(0);

    // epilogue: per acc, tree-max -> first-i equality scan -> global update
    const int pb = r << 4;
    {
      float m = a0[0];
#pragma unroll
      for (int i = 1; i < 16; ++i) m = fmaxf(m, a0[i]);
      int bi = 0;
#pragma unroll
      for (int i = 15; i >= 0; --i) bi = (a0[i] == m) ? i : bi;  // smallest i
      bool upd = m > gbest0;
      gbest0 = upd ? m : gbest0;
      bp0    = upd ? (pb + bi) : bp0;
    }
    {
      float m = a1[0];
#pragma unroll
      for (int i = 1; i < 16; ++i) m = fmaxf(m, a1[i]);
      int bi = 0;
#pragma unroll
      for (int i = 15; i >= 0; --i) bi = (a1[i] == m) ? i : bi;
      bool upd = m > gbest1;
      gbest1 = upd ? m : gbest1;
      bp1    = upd ? (pb + bi) : bp1;
    }
  }

  // all waves done reading z-LDS before the merge overlays it
  __syncthreads();

  // --- decode packed (round,i) -> global k, then exact-tie merges (max) ---
  int bk0, bk1;
  {
    int rr = bp0 >> 4, i = bp0 & 15;
    bk0 = rr * 256 + w * 32 + (i & 3) + 8 * (i >> 2) + 4 * g;
    rr = bp1 >> 4; i = bp1 & 15;
    bk1 = rr * 256 + w * 32 + (i & 3) + 8 * (i >> 2) + 4 * g;
  }
  // merge the two g-halves (same rows, disjoint codes)
  {
    float ob = __shfl_xor(gbest0, 32, 64);
    int   ok = __shfl_xor(bk0, 32, 64);
    if (ob > gbest0 || (ob == gbest0 && ok < bk0)) { gbest0 = ob; bk0 = ok; }
    ob = __shfl_xor(gbest1, 32, 64);
    ok = __shfl_xor(bk1, 32, 64);
    if (ob > gbest1 || (ob == gbest1 && ok < bk1)) { gbest1 = ob; bk1 = ok; }
  }

  // cross-wave merge: 8 tile-waves x 64 rows
  float* fbuf = reinterpret_cast<float*>(lds);          // [8][64]  2KB
  int*   kbuf = reinterpret_cast<int*>(lds + 2048);     // [8][64]  2KB
  int*   ibuf = reinterpret_cast<int*>(lds + 4096);     // [64]
  if (l < 32) {
    fbuf[w * 64 + c]      = gbest0;  kbuf[w * 64 + c]      = bk0;
    fbuf[w * 64 + 32 + c] = gbest1;  kbuf[w * 64 + 32 + c] = bk1;
  }
  __syncthreads();

  if (tid < 64) {
    float bb = fbuf[tid];
    int   kk = kbuf[tid];
#pragma unroll
    for (int ww = 1; ww < 8; ++ww) {
      float b2 = fbuf[ww * 64 + tid];
      int   k2 = kbuf[ww * 64 + tid];
      if (b2 > bb || (b2 == bb && k2 < kk)) { bb = b2; kk = k2; }
    }
    ibuf[tid] = kk;
    out[NQ + 2 + rowbase + tid] = (float)kk;
  }
  __syncthreads();

  // --- gather + losses: 8 threads per row (8 f32 each) ---
  {
    const int row_l = tid >> 3, seg = tid & 7;
    const int idx  = ibuf[row_l];
    const int grow = rowbase + row_l;
    const float4* qp = reinterpret_cast<const float4*>(cb + (size_t)idx * D_DIM + seg * 8);
    const float4* zp = reinterpret_cast<const float4*>(z + (size_t)grow * D_DIM + seg * 8);
    float4*       op = reinterpret_cast<float4*>(out + (size_t)grow * D_DIM + seg * 8);
    float lp = 0.f;
#pragma unroll
    for (int cc = 0; cc < 2; ++cc) {
      float4 qv = qp[cc], zv = zp[cc];
      op[cc] = qv;
      float dx = zv.x - qv.x, dy = zv.y - qv.y;
      float dz = zv.z - qv.z, dw = zv.w - qv.w;
      lp += (dx * dx + dy * dy) + (dz * dz + dw * dw);
    }
#pragma unroll
    for (int off = 32; off > 0; off >>= 1) lp += __shfl_down(lp, off, 64);
    if (l == 0) atomicAdd(ws + WS_LOSS, lp);
  }
}

// ------------------------------------------------- fallback (R4-style; adapted
// to r2n semantics: score = r2n + dot, maximize)
__global__ __launch_bounds__(512, 2) void vq_main_reg(const float* __restrict__ z,
                                                      const float* __restrict__ cb,
                                                      float* __restrict__ ws,
                                                      float* __restrict__ out) {
  __shared__ __attribute__((aligned(16))) unsigned char lds[65536];
  const int tid = threadIdx.x;
  const int w = tid >> 6, l = tid & 63;
  const int rg = w >> 1, sp = w & 1;
  const int c = l & 31, g = l >> 5;
  const int rowbase = blockIdx.x * 128;
  const int myrow = rowbase + rg * 32 + c;

  bf16x8 zh[4], zl[4];
#pragma unroll
  for (int s = 0; s < 4; ++s) {
    const float* zp = z + (size_t)myrow * D_DIM + 16 * s + 8 * g;
    float4 f0 = *reinterpret_cast<const float4*>(zp);
    float4 f1 = *reinterpret_cast<const float4*>(zp + 4);
    float xs[8] = {f0.x, f0.y, f0.z, f0.w, f1.x, f1.y, f1.z, f1.w};
#pragma unroll
    for (int j = 0; j < 8; ++j) {
      __bf16 h = (__bf16)xs[j];
      zh[s][j] = h; zl[s][j] = (__bf16)(xs[j] - (float)h);
    }
  }
  const int st_t01 = tid >> 8;
  const int st_c   = (tid >> 3) & 31;
  const int st_ch  = tid & 7;
  const unsigned st_off = (unsigned)(st_t01 * 16384 + st_ch * 512 + st_c * 16);
  const float* st_g = cb + (size_t)(st_t01 * 32 + st_c) * D_DIM + st_ch * 8;

  float best = -FLT_MAX;
  int   bidx = 0;
  float4 p0 = *reinterpret_cast<const float4*>(st_g);
  float4 p1 = *reinterpret_cast<const float4*>(st_g + 4);
  {
    float xs[8] = {p0.x, p0.y, p0.z, p0.w, p1.x, p1.y, p1.z, p1.w};
    bf16x8 hi, lo;
#pragma unroll
    for (int j = 0; j < 8; ++j) {
      __bf16 h = (__bf16)xs[j];
      hi[j] = h; lo[j] = (__bf16)(xs[j] - (float)h);
    }
    *reinterpret_cast<bf16x8*>(lds + st_off)        = hi;
    *reinterpret_cast<bf16x8*>(lds + st_off + 8192) = lo;
  }
  __syncthreads();
  const unsigned rd_base = (unsigned)(sp * 16384 + c * 16);
  for (int r = 0; r < 128; ++r) {
    const int buf = r & 1;
    if (r < 127) {
      const float* gp = st_g + (size_t)(r + 1) * (64 * D_DIM);
      p0 = *reinterpret_cast<const float4*>(gp);
      p1 = *reinterpret_cast<const float4*>(gp + 4);
    }
    const unsigned b0 = (unsigned)buf * 32768u + rd_base;
    bf16x8 ch[4], cl[4];
#pragma unroll
    for (int s = 0; s < 4; ++s) {
      unsigned off = b0 + (unsigned)((2 * s + g) * 512);
      ch[s] = *reinterpret_cast<const bf16x8*>(lds + off);
      cl[s] = *reinterpret_cast<const bf16x8*>(lds + off + 8192);
    }
    f32x16 acc;
#pragma unroll
    for (int i = 0; i < 16; ++i) acc[i] = 0.f;
#pragma unroll
    for (int s = 0; s < 4; ++s) {
      acc = __builtin_amdgcn_mfma_f32_32x32x16_bf16(ch[s], zh[s], acc, 0, 0, 0);
      acc = __builtin_amdgcn_mfma_f32_32x32x16_bf16(ch[s], zl[s], acc, 0, 0, 0);
      acc = __builtin_amdgcn_mfma_f32_32x32x16_bf16(cl[s], zh[s], acc, 0, 0, 0);
    }
    const int tb = (2 * r + sp) * 32 + 4 * g;
#pragma unroll
    for (int q = 0; q < 4; ++q) {
      float4 rv = *reinterpret_cast<const float4*>(ws + tb + 8 * q);
      float ra[4] = {rv.x, rv.y, rv.z, rv.w};
#pragma unroll
      for (int j = 0; j < 4; ++j) {
        float sc = ra[j] + acc[4 * q + j];   // r2n + dot, maximize
        int kg = tb + 8 * q + j;
        if (sc > best) { best = sc; bidx = kg; }
      }
    }
    if (r < 127) {
      float xs[8] = {p0.x, p0.y, p0.z, p0.w, p1.x, p1.y, p1.z, p1.w};
      bf16x8 hi, lo;
#pragma unroll
      for (int j = 0; j < 8; ++j) {
        __bf16 h = (__bf16)xs[j];
        hi[j] = h; lo[j] = (__bf16)(xs[j] - (float)h);
      }
      unsigned wo = (unsigned)(buf ^ 1) * 32768u + st_off;
      *reinterpret_cast<bf16x8*>(lds + wo)        = hi;
      *reinterpret_cast<bf16x8*>(lds + wo + 8192) = lo;
    }
    __syncthreads();
  }
  {
    float ob = __shfl_xor(best, 32, 64);
    int   oi = __shfl_xor(bidx, 32, 64);
    if (ob > best || (ob == best && oi < bidx)) { best = ob; bidx = oi; }
  }
  float* mf  = reinterpret_cast<float*>(lds);
  int*   mi  = reinterpret_cast<int*>(lds + 1024);
  int*   mix = reinterpret_cast<int*>(lds + 2048);
  if (l < 32) { mf[w * 32 + c] = best; mi[w * 32 + c] = bidx; }
  __syncthreads();
  if (tid < 128) {
    int rgg = tid >> 5, rl = tid & 31;
    float b0 = mf[(2 * rgg) * 32 + rl];     int i0 = mi[(2 * rgg) * 32 + rl];
    float b1 = mf[(2 * rgg + 1) * 32 + rl]; int i1 = mi[(2 * rgg + 1) * 32 + rl];
    int idx = (b1 > b0 || (b1 == b0 && i1 < i0)) ? i1 : i0;
    mix[tid] = idx;
    out[NQ + 2 + rowbase + tid] = (float)idx;
  }
  __syncthreads();
  {
    const int row_l = tid >> 2, seg = tid & 3;
    const int idx  = mix[row_l];
    const int grow = rowbase + row_l;
    const float4* qp = reinterpret_cast<const float4*>(cb + (size_t)idx * D_DIM + seg * 16);
    const float4* zp = reinterpret_cast<const float4*>(z + (size_t)grow * D_DIM + seg * 16);
    float4*       op = reinterpret_cast<float4*>(out + (size_t)grow * D_DIM + seg * 16);
    float lp = 0.f;
#pragma unroll
    for (int cc = 0; cc < 4; ++cc) {
      float4 qv = qp[cc], zv = zp[cc];
      op[cc] = qv;
      float dx = zv.x - qv.x, dy = zv.y - qv.y;
      float dz = zv.z - qv.z, dw = zv.w - qv.w;
      lp += (dx * dx + dy * dy) + (dz * dz + dw * dw);
    }
#pragma unroll
    for (int off = 32; off > 0; off >>= 1) lp += __shfl_down(lp, off, 64);
    if (l == 0) atomicAdd(ws + WS_LOSS, lp);
  }
}

// ------------------------------------------------------------ finalize kernel
__global__ void vq_fin(const float* __restrict__ ws, float* __restrict__ out) {
  float mm = ws[WS_LOSS] * (1.0f / (float)(N_ROWS * D_DIM));
  out[NQ]     = mm;
  out[NQ + 1] = mm;
}

// -------------------------------------------------------------------- launch
extern "C" void kernel_launch(void* const* d_in, const int* in_sizes, int n_in,
                              void* d_out, int out_size, void* d_ws, size_t ws_size,
                              hipStream_t stream) {
  (void)in_sizes; (void)n_in; (void)out_size;
  const float* z  = (const float*)d_in[0];
  const float* cb = (const float*)d_in[1];
  float* out = (float*)d_out;
  float* ws  = (float*)d_ws;

  vq_prep<<<K_CB / 256, 256, 0, stream>>>(cb, ws);
  if (ws_size >= WS_NEED) {
    vq_split<<<256, 256, 0, stream>>>(cb, ws);
    vq_gd4<<<N_ROWS / 64, 512, 0, stream>>>(z, cb, ws, out);
  } else {
    vq_main_reg<<<N_ROWS / 128, 512, 0, stream>>>(z, cb, ws, out);
  }
  vq_fin<<<1, 1, 0, stream>>>(ws, out);
}